// Round 8
// baseline (12036.565 us; speedup 1.0000x reference)
//
#include <hip/hip_runtime.h>

#define BSZ 512
#define LSEQ 128
#define HH 512
#define AA 128
#define NC 640    // H + A
#define N1 1152   // H + NC
#define KD 512
#define SBR 16    // batch rows per scan block

typedef short s8v __attribute__((ext_vector_type(8)));
typedef float f4v __attribute__((ext_vector_type(4)));

__device__ __forceinline__ unsigned short bf16_rne(float f) {
  unsigned int u = __float_as_uint(f);
  u += 0x7fffu + ((u >> 16) & 1u);
  return (unsigned short)(u >> 16);
}
__device__ __forceinline__ float bf16_tof(unsigned short s) {
  return __uint_as_float(((unsigned int)s) << 16);
}
__device__ __forceinline__ float fast_tanh(float x) {
  float t = __expf(2.f * x);
  return 1.f - 2.f / (t + 1.f);
}

// ---------------- prep kernels ----------------

__global__ __launch_bounds__(256) void concat_k(
    const float* __restrict__ U, const float* __restrict__ Ua1,
    const float* __restrict__ W, const float* __restrict__ Wa1,
    const float* __restrict__ bb, const float* __restrict__ ba1,
    float* __restrict__ Ucat, float* __restrict__ Wcat, float* __restrict__ bias2)
{
  int idx = blockIdx.x * 256 + threadIdx.x;
  if (idx < KD * NC) {
    int k = idx / NC, c = idx % NC;
    Ucat[idx] = (c < HH) ? U[k * HH + c] : Ua1[k * AA + (c - HH)];
    Wcat[idx] = (c < HH) ? W[k * HH + c] : Wa1[k * AA + (c - HH)];
  }
  if (idx < NC) bias2[idx] = (idx < HH) ? bb[idx] : ba1[idx - HH];
}

__global__ __launch_bounds__(NC) void comb_k(
    const float* __restrict__ Wemb, const float* __restrict__ Wcat,
    float* __restrict__ Wcomb)
{
  __shared__ float arow[KD];
  int m = blockIdx.x, n = threadIdx.x;
  for (int i = threadIdx.x; i < KD; i += NC) arow[i] = Wemb[m * HH + i];
  __syncthreads();
  float a0 = 0.f, a1 = 0.f, a2 = 0.f, a3 = 0.f;
  for (int k = 0; k < KD; k += 4) {
    a0 = fmaf(arow[k],     Wcat[(size_t)(k)     * NC + n], a0);
    a1 = fmaf(arow[k + 1], Wcat[(size_t)(k + 1) * NC + n], a1);
    a2 = fmaf(arow[k + 2], Wcat[(size_t)(k + 2) * NC + n], a2);
    a3 = fmaf(arow[k + 3], Wcat[(size_t)(k + 3) * NC + n], a3);
  }
  Wcomb[(size_t)m * NC + n] = (a0 + a1) + (a2 + a3);
}

__global__ __launch_bounds__(NC) void bcomb_k(
    const float* __restrict__ bemb, const float* __restrict__ Wcat,
    const float* __restrict__ bias2, float* __restrict__ bias1)
{
  __shared__ float be[KD];
  int n = threadIdx.x;
  for (int i = n; i < KD; i += NC) be[i] = bemb[i];
  __syncthreads();
  float acc = 0.f;
  for (int k = 0; k < KD; ++k) acc = fmaf(be[k], Wcat[(size_t)k * NC + n], acc);
  bias1[HH + n] = acc + bias2[n];
  if (n < HH) bias1[n] = bemb[n];
}

// transpose + split f32 [KD][N] -> bf16 hi/lo [N][KD]
__global__ __launch_bounds__(256) void tsplit_k(
    const float* __restrict__ src, int N,
    unsigned short* __restrict__ dsth, unsigned short* __restrict__ dstl, int row_off)
{
  __shared__ float tile[32][33];
  int k0 = blockIdx.x * 32, n0 = blockIdx.y * 32;
  int tx = threadIdx.x & 31, ty = threadIdx.x >> 5;
  for (int i = ty; i < 32; i += 8) {
    int n = n0 + tx;
    tile[i][tx] = (n < N) ? src[(size_t)(k0 + i) * N + n] : 0.f;
  }
  __syncthreads();
  for (int i = ty; i < 32; i += 8) {
    int n = n0 + i;
    if (n >= N) continue;
    float v = tile[tx][i];
    unsigned short h = bf16_rne(v);
    unsigned short l = bf16_rne(v - bf16_tof(h));
    dsth[(size_t)(row_off + n) * KD + k0 + tx] = h;
    dstl[(size_t)(row_off + n) * KD + k0 + tx] = l;
  }
}

// split f32 -> bf16 hi/lo planes (flat)
__global__ __launch_bounds__(256) void splitx_k(
    const float* __restrict__ x, unsigned short* __restrict__ xh,
    unsigned short* __restrict__ xl, int n4)
{
  int i = blockIdx.x * 256 + threadIdx.x;
  if (i >= n4) return;
  const float4 v = *(const float4*)&x[(size_t)i * 4];
  unsigned short h0 = bf16_rne(v.x), h1 = bf16_rne(v.y), h2 = bf16_rne(v.z), h3 = bf16_rne(v.w);
  unsigned short l0 = bf16_rne(v.x - bf16_tof(h0));
  unsigned short l1 = bf16_rne(v.y - bf16_tof(h1));
  unsigned short l2 = bf16_rne(v.z - bf16_tof(h2));
  unsigned short l3 = bf16_rne(v.w - bf16_tof(h3));
  *(ushort4*)&xh[(size_t)i * 4] = make_ushort4(h0, h1, h2, h3);
  *(ushort4*)&xl[(size_t)i * 4] = make_ushort4(l0, l1, l2, l3);
}

// ---------------- split-bf16 3-term MFMA GEMM ----------------
template<int REMAP, int OMODE>
__global__ __launch_bounds__(256, 2) void gemm_k(
    const unsigned short* __restrict__ Ah, const unsigned short* __restrict__ Al,
    const unsigned short* __restrict__ BTh, const unsigned short* __restrict__ BTl,
    const float* __restrict__ bias, int NT, int c0,
    unsigned short* __restrict__ o_xeh, unsigned short* __restrict__ o_xel,
    float* __restrict__ o_xp)
{
  __shared__ __align__(16) unsigned short As_h[128][72];
  __shared__ __align__(16) unsigned short As_l[128][72];
  __shared__ __align__(16) unsigned short Bs_h[128][72];
  __shared__ __align__(16) unsigned short Bs_l[128][72];
  const int tid = threadIdx.x;
  const int lane = tid & 63, w = tid >> 6;
  const int wm = w >> 1, wn = w & 1;
  const int m0 = (blockIdx.x / NT) * 128, n0 = (blockIdx.x % NT) * 128;

  f4v acc[4][4];
#pragma unroll
  for (int i = 0; i < 4; ++i)
#pragma unroll
    for (int j = 0; j < 4; ++j) acc[i][j] = (f4v){0.f, 0.f, 0.f, 0.f};

  for (int kt = 0; kt < KD; kt += 64) {
    __syncthreads();
#pragma unroll
    for (int p = 0; p < 4; ++p) {
      int li = tid + p * 256;
      int row = li >> 3, kc = (li & 7) << 3;
      int m = m0 + row;
      int arow = REMAP ? ((m & 511) * 128 + c0 + (m >> 9)) : m;
      *(s8v*)&As_h[row][kc] = *(const s8v*)&Ah[(size_t)arow * KD + kt + kc];
      *(s8v*)&As_l[row][kc] = *(const s8v*)&Al[(size_t)arow * KD + kt + kc];
      *(s8v*)&Bs_h[row][kc] = *(const s8v*)&BTh[(size_t)(n0 + row) * KD + kt + kc];
      *(s8v*)&Bs_l[row][kc] = *(const s8v*)&BTl[(size_t)(n0 + row) * KD + kt + kc];
    }
    __syncthreads();
#pragma unroll
    for (int kk = 0; kk < 2; ++kk) {
      const int kb = kk * 32 + (lane >> 4) * 8;
      s8v ah[4], alo[4], bh[4], blo[4];
#pragma unroll
      for (int i = 0; i < 4; ++i) {
        int ra = wm * 64 + i * 16 + (lane & 15);
        int rb = wn * 64 + i * 16 + (lane & 15);
        ah[i]  = *(const s8v*)&As_h[ra][kb];
        alo[i] = *(const s8v*)&As_l[ra][kb];
        bh[i]  = *(const s8v*)&Bs_h[rb][kb];
        blo[i] = *(const s8v*)&Bs_l[rb][kb];
      }
#pragma unroll
      for (int mi = 0; mi < 4; ++mi)
#pragma unroll
        for (int ni = 0; ni < 4; ++ni) {
          acc[mi][ni] = __builtin_amdgcn_mfma_f32_16x16x32_bf16(alo[mi], bh[ni], acc[mi][ni], 0, 0, 0);
          acc[mi][ni] = __builtin_amdgcn_mfma_f32_16x16x32_bf16(ah[mi], blo[ni], acc[mi][ni], 0, 0, 0);
          acc[mi][ni] = __builtin_amdgcn_mfma_f32_16x16x32_bf16(ah[mi], bh[ni], acc[mi][ni], 0, 0, 0);
        }
    }
  }
#pragma unroll
  for (int mi = 0; mi < 4; ++mi) {
#pragma unroll
    for (int ni = 0; ni < 4; ++ni) {
      int n = n0 + wn * 64 + ni * 16 + (lane & 15);
      float bv = bias[n];
#pragma unroll
      for (int r = 0; r < 4; ++r) {
        int m = m0 + wm * 64 + mi * 16 + (lane >> 4) * 4 + r;
        float val = acc[mi][ni][r] + bv;
        if (OMODE == 1) {
          if (n < HH) {
            unsigned short hb = bf16_rne(val);
            unsigned short lb = bf16_rne(val - bf16_tof(hb));
            o_xeh[(size_t)m * KD + n] = hb;
            o_xel[(size_t)m * KD + n] = lb;
          } else {
            o_xp[(size_t)m * NC + (n - HH)] = val;
          }
        } else {
          o_xp[(size_t)m * NC + n] = val;
        }
      }
    }
  }
}

// ---------------- fused 3-layer MFMA scan ----------------
struct LayerArgs {
  const unsigned short* xin_h; const unsigned short* xin_l;
  const float* xp;
  const int* ain; const int* nin;
  int* aout; int* nout;
  unsigned short* hout_h; unsigned short* hout_l;
  unsigned int* hst;
  int* aT; int* dT;
  float* dd;
  int LL, c0, FIRST, active;
};
struct Args3 { LayerArgs l[3]; };

// 96 blocks x 512 threads; block b: layer = b>>5, rowblock = b&31 (16 rows).
// Phase A: B staged via global_load_lds into wave-private 4-deep LDS ring,
// counted vmcnt(6). T2 both-sides permutation: lane l DMAs (row=l&15,
// kchunk=l>>4) so the reader (row=ar,kc=g) = lane g*16+ar reads its OWN 16B
// at byte lane*16 -> conflict-free linear ds_read.
__global__ __launch_bounds__(512) void scan3_k(
    Args3 A3,
    const unsigned short* __restrict__ UTh, const unsigned short* __restrict__ UTl,
    const float* __restrict__ Wa2, const float* __restrict__ ba2,
    const int* __restrict__ mask, int CH)
{
  const int lay = blockIdx.x >> 5;
  const LayerArgs La = A3.l[lay];
  if (!La.active) return;

  __shared__ __align__(16) unsigned short hh[SBR][520];
  __shared__ __align__(16) unsigned short hl[SBR][520];
  __shared__ __align__(16) unsigned short ring[8][4][2][512]; // wave x slot x plane x 1KB
  __shared__ float ya[SBR][644];
  __shared__ float pol[SBR][AA];
  __shared__ float sWa2[AA * 2];
  __shared__ float sba2[2];
  __shared__ int gB[SBR], gH[SBR], gX[SBR], gDP[SBR], sAT[SBR], sDT[SBR];

  const int tid = threadIdx.x;
  const int lane = tid & 63, w = tid >> 6;
  const int b0 = (blockIdx.x & 31) * SBR;
  const int ar = lane & 15, g = lane >> 4;
  const int cola = tid & 127, rb = tid >> 7;

  if (tid < AA * 2) sWa2[tid] = Wa2[tid];
  if (tid < 2) sba2[tid] = ba2[tid];
  if (tid < SBR) {
    sAT[tid] = La.FIRST ? 0 : La.aT[b0 + tid];
    sDT[tid] = La.FIRST ? 0 : La.dT[b0 + tid];
  }
#pragma unroll
  for (int r = 0; r < SBR; ++r) {
    unsigned int u = La.FIRST ? 0u : La.hst[(size_t)(b0 + r) * KD + tid];
    hh[r][tid] = (unsigned short)(u >> 16);
    hl[r][tid] = (unsigned short)(u & 0xffff);
  }
  __syncthreads();

  // staging source: lane l covers (row = l&15, kchunk = l>>4) of each 16x32 tile
  const size_t lane_soff = (size_t)(lane & 15) * KD + (size_t)(lane >> 4) * 8;
  const unsigned short* __restrict__ uth_base = UTh + (size_t)w * 80 * KD + lane_soff;
  const unsigned short* __restrict__ utl_base = UTl + (size_t)w * 80 * KD + lane_soff;

  const int br0 = b0 + 2 * w;
  const int br1 = br0 + 1;

  for (int tl = 0; tl < CH; ++tl) {
    const int t = La.c0 + tl;
    const size_t xrow = (size_t)tl * BSZ + b0;

    // drain so vmcnt counting below is exact
    asm volatile("s_waitcnt vmcnt(0)" ::: "memory");

    // gate scalars (wave-uniform)
    int A0 = (La.ain && t < LSEQ - 1) ? La.ain[(t + 1) * BSZ + br0] : 0;
    int A1 = (La.ain && t < LSEQ - 1) ? La.ain[(t + 1) * BSZ + br1] : 0;
    int DP0 = La.nin ? La.nin[t * BSZ + br0] : mask[br0 * LSEQ + t];
    int DP1 = La.nin ? La.nin[t * BSZ + br1] : mask[br1 * LSEQ + t];
    int mt0 = mask[br0 * LSEQ + t];
    int mt1 = mask[br1 * LSEQ + t];
    int mn0 = (t < LSEQ - 1) ? mask[br0 * LSEQ + t + 1] : 0;
    int mn1 = (t < LSEQ - 1) ? mask[br1 * LSEQ + t + 1] : 0;

    // ---- phase A: Y = h @ Ucat; LDS-ring staged B, counted vmcnt ----
    f4v acc[5];
#pragma unroll
    for (int nt = 0; nt < 5; ++nt) acc[nt] = (f4v){0.f, 0.f, 0.f, 0.f};

    auto stage = [&](int j) {   // j in [0,80): tile (ks=j/5, nt=j%5) -> slot j&3
      const int ksj = j / 5, ntj = j - ksj * 5;
      const int s = j & 3;
      const unsigned short* gh = uth_base + (size_t)ntj * 16 * KD + ksj * 32;
      const unsigned short* gl = utl_base + (size_t)ntj * 16 * KD + ksj * 32;
      __builtin_amdgcn_global_load_lds(
          (const __attribute__((address_space(1))) void*)gh,
          (__attribute__((address_space(3))) void*)&ring[w][s][0][0], 16, 0, 0);
      __builtin_amdgcn_global_load_lds(
          (const __attribute__((address_space(1))) void*)gl,
          (__attribute__((address_space(3))) void*)&ring[w][s][1][0], 16, 0, 0);
    };

    stage(0); stage(1); stage(2);
#pragma unroll
    for (int ks = 0; ks < 16; ++ks) {
      const int ko = ks * 32 + g * 8;
      s8v ah = *(const s8v*)&hh[ar][ko];
      s8v al = *(const s8v*)&hl[ar][ko];
#pragma unroll
      for (int nt = 0; nt < 5; ++nt) {
        const int j = ks * 5 + nt;
        int j3 = j + 3; if (j3 >= 80) j3 -= 80;   // wrap keeps 8 loads in flight
        stage(j3);
        asm volatile("s_waitcnt vmcnt(6)" ::: "memory");
        const int s = j & 3;
        s8v bh = *(const s8v*)&ring[w][s][0][lane * 8];   // own 16B -> linear, no conflicts
        s8v bl = *(const s8v*)&ring[w][s][1][lane * 8];
        acc[nt] = __builtin_amdgcn_mfma_f32_16x16x32_bf16(al, bh, acc[nt], 0, 0, 0);
        acc[nt] = __builtin_amdgcn_mfma_f32_16x16x32_bf16(ah, bl, acc[nt], 0, 0, 0);
        acc[nt] = __builtin_amdgcn_mfma_f32_16x16x32_bf16(ah, bh, acc[nt], 0, 0, 0);
      }
    }
#pragma unroll
    for (int nt = 0; nt < 5; ++nt)
#pragma unroll
      for (int r = 0; r < 4; ++r)
        ya[g * 4 + r][w * 80 + nt * 16 + ar] = acc[nt][r];
    __syncthreads();

    // ---- phase B: hnew (regs) + pol (LDS) ----
    const float* __restrict__ xpb = La.xp + xrow * NC;
    float hnew_r[16];
#pragma unroll
    for (int r = 0; r < 16; ++r) hnew_r[r] = fast_tanh(xpb[(size_t)r * NC + tid] + ya[r][tid]);
#pragma unroll
    for (int q = 0; q < 4; ++q) {
      int r = q * 4 + rb;
      pol[r][cola] = fmaxf(xpb[(size_t)r * NC + HH + cola] + ya[r][HH + cola], 0.f);
    }
    __syncthreads();

    // ---- phase C+D: logits + gating (wave-local) ----
    {
      const int g16 = lane >> 4, li = lane & 15;
      const int rr = 2 * w + (g16 >> 1), j = g16 & 1;
      float p = 0.f;
#pragma unroll
      for (int i = 0; i < 8; ++i)
        p = fmaf(pol[rr][li + 16 * i], sWa2[(li + 16 * i) * 2 + j], p);
      p += __shfl_xor(p, 1); p += __shfl_xor(p, 2);
      p += __shfl_xor(p, 4); p += __shfl_xor(p, 8);
      float l00 = __shfl(p, 0)  + sba2[0];
      float l01 = __shfl(p, 16) + sba2[1];
      float l10 = __shfl(p, 32) + sba2[0];
      float l11 = __shfl(p, 48) + sba2[1];
      int E0 = mt0 * (1 - mn0), E1 = mt1 * (1 - mn1);
      int act0 = (l00 >= l01) ? 1 : 0;
      if (A0 > 0) act0 = 1;
      if (La.LL) act0 = 1;
      if (E0 > 0) act0 = 0;
      int act1 = (l10 >= l11) ? 1 : 0;
      if (A1 > 0) act1 = 1;
      if (La.LL) act1 = 1;
      if (E1 > 0) act1 = 0;
      int DT0 = sDT[2 * w], DT1 = sDT[2 * w + 1];
      int both0  = (1 - A0) * DP0 * act0 * DT0;
      int honly0 = DT0 * act0 * (A0 + (1 - A0) * (1 - DP0));
      int xonly0 = DP0 * (1 - A0) * (1 - act0 + act0 * (1 - DT0));
      int ndm0 = DP0 * (both0 + xonly0 + honly0);
      int aout0 = DP0 ? act0 : sAT[2 * w];
      int both1  = (1 - A1) * DP1 * act1 * DT1;
      int honly1 = DT1 * act1 * (A1 + (1 - A1) * (1 - DP1));
      int xonly1 = DP1 * (1 - A1) * (1 - act1 + act1 * (1 - DT1));
      int ndm1 = DP1 * (both1 + xonly1 + honly1);
      int aout1 = DP1 ? act1 : sAT[2 * w + 1];
      if (lane == 0) {
        gB[2 * w] = both0; gH[2 * w] = honly0; gX[2 * w] = xonly0; gDP[2 * w] = DP0;
        sAT[2 * w] = aout0; sDT[2 * w] = ndm0;
        gB[2 * w + 1] = both1; gH[2 * w + 1] = honly1; gX[2 * w + 1] = xonly1; gDP[2 * w + 1] = DP1;
        sAT[2 * w + 1] = aout1; sDT[2 * w + 1] = ndm1;
        if (La.aout) { La.aout[t * BSZ + br0] = aout0; La.aout[t * BSZ + br1] = aout1; }
        if (La.nout) { La.nout[t * BSZ + br0] = ndm0; La.nout[t * BSZ + br1] = ndm1; }
      }
    }
    __syncthreads();

    // ---- phase E: h update + outputs ----
#pragma unroll
    for (int r = 0; r < 16; ++r) {
      float vold = bf16_tof(hh[r][tid]) + bf16_tof(hl[r][tid]);
      float v;
      if (gB[r]) v = hnew_r[r];
      else if (gH[r]) v = vold;
      else if (gX[r]) {
        v = bf16_tof(La.xin_h[(xrow + r) * KD + tid]) + bf16_tof(La.xin_l[(xrow + r) * KD + tid]);
      } else v = 0.f;
      if (!gDP[r]) v = vold;
      unsigned short hi = bf16_rne(v);
      unsigned short lo = bf16_rne(v - bf16_tof(hi));
      hh[r][tid] = hi; hl[r][tid] = lo;
      if (La.hout_h) {
        La.hout_h[(xrow + r) * KD + tid] = hi;
        La.hout_l[(xrow + r) * KD + tid] = lo;
      }
      if (La.dd && t == LSEQ - 1) La.dd[(size_t)(b0 + r) * KD + tid] = v;
    }
    __syncthreads();
  }

#pragma unroll
  for (int r = 0; r < SBR; ++r)
    La.hst[(size_t)(b0 + r) * KD + tid] = ((unsigned int)hh[r][tid] << 16) | hl[r][tid];
  if (tid < SBR) { La.aT[b0 + tid] = sAT[tid]; La.dT[b0 + tid] = sDT[tid]; }
}

// ---------------- host ----------------
extern "C" void kernel_launch(void* const* d_in, const int* in_sizes, int n_in,
                              void* d_out, int out_size, void* d_ws, size_t ws_size,
                              hipStream_t stream)
{
  (void)in_sizes; (void)n_in; (void)out_size;
  const float* x    = (const float*)d_in[0];
  const int*   mask = (const int*)d_in[2];
  const float* Wemb = (const float*)d_in[3];
  const float* bemb = (const float*)d_in[4];
  const float* Wm   = (const float*)d_in[5];
  const float* Um   = (const float*)d_in[6];
  const float* bm   = (const float*)d_in[7];
  const float* Wa1  = (const float*)d_in[8];
  const float* Ua1  = (const float*)d_in[9];
  const float* ba1  = (const float*)d_in[10];
  const float* Wa2  = (const float*)d_in[11];
  const float* ba2  = (const float*)d_in[12];
  float* out = (float*)d_out;

  const size_t FIXED = (size_t)160 << 20;
  const size_t PER_CH = (size_t)12 << 20;
  int CH = 4;
  {
    const int cands[3] = {16, 8, 4};
    for (int i = 0; i < 3; ++i)
      if (FIXED + (size_t)cands[i] * PER_CH <= ws_size) { CH = cands[i]; break; }
  }
  const int NCH = LSEQ / CH;

  char* p = (char*)d_ws;
  auto alloc = [&](size_t bytes) { char* r = p; p += (bytes + 255) & ~(size_t)255; return r; };

  float* Ucat  = (float*)alloc((size_t)KD * NC * 4);
  float* Wcat  = (float*)alloc((size_t)KD * NC * 4);
  float* Wcomb = (float*)alloc((size_t)KD * NC * 4);
  float* bias1 = (float*)alloc(N1 * 4);
  float* bias2 = (float*)alloc(NC * 4);
  unsigned short* BT1h = (unsigned short*)alloc((size_t)N1 * KD * 2);
  unsigned short* BT1l = (unsigned short*)alloc((size_t)N1 * KD * 2);
  unsigned short* BT2h = (unsigned short*)alloc((size_t)NC * KD * 2);
  unsigned short* BT2l = (unsigned short*)alloc((size_t)NC * KD * 2);
  unsigned short* UTh  = (unsigned short*)alloc((size_t)NC * KD * 2);
  unsigned short* UTl  = (unsigned short*)alloc((size_t)NC * KD * 2);
  int* acts0 = (int*)alloc((size_t)LSEQ * BSZ * 4);
  int* ndms0 = (int*)alloc((size_t)LSEQ * BSZ * 4);
  int* acts1 = (int*)alloc((size_t)LSEQ * BSZ * 4);
  int* ndms1 = (int*)alloc((size_t)LSEQ * BSZ * 4);
  unsigned int* hst0 = (unsigned int*)alloc((size_t)BSZ * KD * 4);
  unsigned int* hst1 = (unsigned int*)alloc((size_t)BSZ * KD * 4);
  unsigned int* hst2 = (unsigned int*)alloc((size_t)BSZ * KD * 4);
  int* aT0 = (int*)alloc(BSZ * 4); int* dT0 = (int*)alloc(BSZ * 4);
  int* aT1 = (int*)alloc(BSZ * 4); int* dT1 = (int*)alloc(BSZ * 4);
  int* aT2 = (int*)alloc(BSZ * 4); int* dT2 = (int*)alloc(BSZ * 4);
  const size_t XEL = (size_t)BSZ * LSEQ * KD;
  unsigned short* xph = (unsigned short*)alloc(XEL * 2);
  unsigned short* xpl = (unsigned short*)alloc(XEL * 2);
  const size_t CE = (size_t)CH * BSZ * KD;
  unsigned short* xeh = (unsigned short*)alloc(CE * 2);
  unsigned short* xel = (unsigned short*)alloc(CE * 2);
  unsigned short* h0h[3], *h0l[3], *h1h[3], *h1l[3];
  for (int i = 0; i < 3; ++i) {
    h0h[i] = (unsigned short*)alloc(CE * 2); h0l[i] = (unsigned short*)alloc(CE * 2);
    h1h[i] = (unsigned short*)alloc(CE * 2); h1l[i] = (unsigned short*)alloc(CE * 2);
  }
  float* XP0 = (float*)alloc((size_t)CH * BSZ * NC * 4);
  float* XP1 = (float*)alloc((size_t)CH * BSZ * NC * 4);
  float* XP2 = (float*)alloc((size_t)CH * BSZ * NC * 4);

  concat_k<<<(KD * NC + 255) / 256, 256, 0, stream>>>(Um, Ua1, Wm, Wa1, bm, ba1, Ucat, Wcat, bias2);
  comb_k<<<KD, NC, 0, stream>>>(Wemb, Wcat, Wcomb);
  bcomb_k<<<1, NC, 0, stream>>>(bemb, Wcat, bias2, bias1);
  tsplit_k<<<dim3(16, 16), 256, 0, stream>>>(Wemb, HH, BT1h, BT1l, 0);
  tsplit_k<<<dim3(16, 20), 256, 0, stream>>>(Wcomb, NC, BT1h, BT1l, HH);
  tsplit_k<<<dim3(16, 20), 256, 0, stream>>>(Wcat, NC, BT2h, BT2l, 0);
  tsplit_k<<<dim3(16, 20), 256, 0, stream>>>(Ucat, NC, UTh, UTl, 0);
  splitx_k<<<(int)((XEL / 4 + 255) / 256), 256, 0, stream>>>(x, xph, xpl, (int)(XEL / 4));

  for (int s = 0; s < NCH + 4; ++s) {
    const int c0i = s, c1i = s - 2, c2i = s - 4;
    const bool a0 = (c0i >= 0 && c0i < NCH);
    const bool a1 = (c1i >= 0 && c1i < NCH);
    const bool a2 = (c2i >= 0 && c2i < NCH);
    const int s0 = a0 ? (c0i % 3) : 0, s1 = a1 ? (c1i % 3) : 0, s2 = a2 ? (c2i % 3) : 0;

    if (a0) gemm_k<1, 1><<<CH * 36, 256, 0, stream>>>(xph, xpl, BT1h, BT1l, bias1, 9, c0i * CH,
                                                      xeh, xel, XP0);
    if (a1) gemm_k<0, 2><<<CH * 20, 256, 0, stream>>>(h0h[s1], h0l[s1], BT2h, BT2l, bias2, 5, 0,
                                                      nullptr, nullptr, XP1);
    if (a2) gemm_k<0, 2><<<CH * 20, 256, 0, stream>>>(h1h[s2], h1l[s2], BT2h, BT2l, bias2, 5, 0,
                                                      nullptr, nullptr, XP2);

    Args3 A3{};
    A3.l[0] = LayerArgs{ xeh, xel, XP0, nullptr, nullptr, acts0, ndms0,
                         h0h[s0], h0l[s0], hst0, aT0, dT0, nullptr,
                         0, c0i * CH, c0i == 0, a0 ? 1 : 0 };
    A3.l[1] = LayerArgs{ h0h[s1], h0l[s1], XP1, acts0, ndms0, acts1, ndms1,
                         h1h[s1], h1l[s1], hst1, aT1, dT1, nullptr,
                         0, c1i * CH, c1i == 0, a1 ? 1 : 0 };
    A3.l[2] = LayerArgs{ h1h[s2], h1l[s2], XP2, acts1, ndms1, nullptr, nullptr,
                         nullptr, nullptr, hst2, aT2, dT2, out,
                         1, c2i * CH, c2i == 0, a2 ? 1 : 0 };
    scan3_k<<<96, 512, 0, stream>>>(A3, UTh, UTl, Wa2, ba2, mask, CH);
  }
}

// Round 9
// 8435.578 us; speedup vs baseline: 1.4269x; 1.4269x over previous
//
#include <hip/hip_runtime.h>

#define BSZ 512
#define LSEQ 128
#define HH 512
#define AA 128
#define NC 640    // H + A
#define N1 1152   // H + NC
#define KD 512
#define SBR 16    // batch rows per scan block

typedef short s8v __attribute__((ext_vector_type(8)));
typedef float f4v __attribute__((ext_vector_type(4)));

__device__ __forceinline__ unsigned short bf16_rne(float f) {
  unsigned int u = __float_as_uint(f);
  u += 0x7fffu + ((u >> 16) & 1u);
  return (unsigned short)(u >> 16);
}
__device__ __forceinline__ float bf16_tof(unsigned short s) {
  return __uint_as_float(((unsigned int)s) << 16);
}
__device__ __forceinline__ float fast_tanh(float x) {
  float t = __expf(2.f * x);
  return 1.f - 2.f / (t + 1.f);
}

// ---------------- prep kernels ----------------

__global__ __launch_bounds__(256) void concat_k(
    const float* __restrict__ U, const float* __restrict__ Ua1,
    const float* __restrict__ W, const float* __restrict__ Wa1,
    const float* __restrict__ bb, const float* __restrict__ ba1,
    float* __restrict__ Ucat, float* __restrict__ Wcat, float* __restrict__ bias2)
{
  int idx = blockIdx.x * 256 + threadIdx.x;
  if (idx < KD * NC) {
    int k = idx / NC, c = idx % NC;
    Ucat[idx] = (c < HH) ? U[k * HH + c] : Ua1[k * AA + (c - HH)];
    Wcat[idx] = (c < HH) ? W[k * HH + c] : Wa1[k * AA + (c - HH)];
  }
  if (idx < NC) bias2[idx] = (idx < HH) ? bb[idx] : ba1[idx - HH];
}

__global__ __launch_bounds__(NC) void comb_k(
    const float* __restrict__ Wemb, const float* __restrict__ Wcat,
    float* __restrict__ Wcomb)
{
  __shared__ float arow[KD];
  int m = blockIdx.x, n = threadIdx.x;
  for (int i = threadIdx.x; i < KD; i += NC) arow[i] = Wemb[m * HH + i];
  __syncthreads();
  float a0 = 0.f, a1 = 0.f, a2 = 0.f, a3 = 0.f;
  for (int k = 0; k < KD; k += 4) {
    a0 = fmaf(arow[k],     Wcat[(size_t)(k)     * NC + n], a0);
    a1 = fmaf(arow[k + 1], Wcat[(size_t)(k + 1) * NC + n], a1);
    a2 = fmaf(arow[k + 2], Wcat[(size_t)(k + 2) * NC + n], a2);
    a3 = fmaf(arow[k + 3], Wcat[(size_t)(k + 3) * NC + n], a3);
  }
  Wcomb[(size_t)m * NC + n] = (a0 + a1) + (a2 + a3);
}

__global__ __launch_bounds__(NC) void bcomb_k(
    const float* __restrict__ bemb, const float* __restrict__ Wcat,
    const float* __restrict__ bias2, float* __restrict__ bias1)
{
  __shared__ float be[KD];
  int n = threadIdx.x;
  for (int i = n; i < KD; i += NC) be[i] = bemb[i];
  __syncthreads();
  float acc = 0.f;
  for (int k = 0; k < KD; ++k) acc = fmaf(be[k], Wcat[(size_t)k * NC + n], acc);
  bias1[HH + n] = acc + bias2[n];
  if (n < HH) bias1[n] = bemb[n];
}

// transpose + split f32 [KD][N] -> bf16 hi/lo [N][KD]
__global__ __launch_bounds__(256) void tsplit_k(
    const float* __restrict__ src, int N,
    unsigned short* __restrict__ dsth, unsigned short* __restrict__ dstl, int row_off)
{
  __shared__ float tile[32][33];
  int k0 = blockIdx.x * 32, n0 = blockIdx.y * 32;
  int tx = threadIdx.x & 31, ty = threadIdx.x >> 5;
  for (int i = ty; i < 32; i += 8) {
    int n = n0 + tx;
    tile[i][tx] = (n < N) ? src[(size_t)(k0 + i) * N + n] : 0.f;
  }
  __syncthreads();
  for (int i = ty; i < 32; i += 8) {
    int n = n0 + i;
    if (n >= N) continue;
    float v = tile[tx][i];
    unsigned short h = bf16_rne(v);
    unsigned short l = bf16_rne(v - bf16_tof(h));
    dsth[(size_t)(row_off + n) * KD + k0 + tx] = h;
    dstl[(size_t)(row_off + n) * KD + k0 + tx] = l;
  }
}

// split f32 -> bf16 hi/lo planes (flat)
__global__ __launch_bounds__(256) void splitx_k(
    const float* __restrict__ x, unsigned short* __restrict__ xh,
    unsigned short* __restrict__ xl, int n4)
{
  int i = blockIdx.x * 256 + threadIdx.x;
  if (i >= n4) return;
  const float4 v = *(const float4*)&x[(size_t)i * 4];
  unsigned short h0 = bf16_rne(v.x), h1 = bf16_rne(v.y), h2 = bf16_rne(v.z), h3 = bf16_rne(v.w);
  unsigned short l0 = bf16_rne(v.x - bf16_tof(h0));
  unsigned short l1 = bf16_rne(v.y - bf16_tof(h1));
  unsigned short l2 = bf16_rne(v.z - bf16_tof(h2));
  unsigned short l3 = bf16_rne(v.w - bf16_tof(h3));
  *(ushort4*)&xh[(size_t)i * 4] = make_ushort4(h0, h1, h2, h3);
  *(ushort4*)&xl[(size_t)i * 4] = make_ushort4(l0, l1, l2, l3);
}

// pack UT hi/lo into per-wave, consumption-ordered contiguous tiles:
// pk[(w*80 + ks*5 + nt)*1024 + p*512 + lane*8 + e] =
//   UT_p[(w*80 + nt*16 + (lane&15))*KD + ks*32 + (lane>>4)*8 + e]
__global__ __launch_bounds__(256) void upack_k(
    const unsigned short* __restrict__ UTh, const unsigned short* __restrict__ UTl,
    unsigned short* __restrict__ pk)
{
  int gid = blockIdx.x * 256 + threadIdx.x;   // tile*128 + p*64 + lane
  if (gid >= 8 * 80 * 2 * 64) return;
  int lane = gid & 63;
  int p = (gid >> 6) & 1;
  int tile = gid >> 7;                        // w*80 + ks*5 + nt
  int w = tile / 80;
  int rem = tile - w * 80;
  int ks = rem / 5, nt = rem - ks * 5;
  const unsigned short* src = p ? UTl : UTh;
  size_t soff = (size_t)(w * 80 + nt * 16 + (lane & 15)) * KD + ks * 32 + (lane >> 4) * 8;
  *(s8v*)&pk[(size_t)gid * 8] = *(const s8v*)&src[soff];
}

// ---------------- split-bf16 3-term MFMA GEMM ----------------
template<int REMAP, int OMODE>
__global__ __launch_bounds__(256, 2) void gemm_k(
    const unsigned short* __restrict__ Ah, const unsigned short* __restrict__ Al,
    const unsigned short* __restrict__ BTh, const unsigned short* __restrict__ BTl,
    const float* __restrict__ bias, int NT, int c0,
    unsigned short* __restrict__ o_xeh, unsigned short* __restrict__ o_xel,
    float* __restrict__ o_xp)
{
  __shared__ __align__(16) unsigned short As_h[128][72];
  __shared__ __align__(16) unsigned short As_l[128][72];
  __shared__ __align__(16) unsigned short Bs_h[128][72];
  __shared__ __align__(16) unsigned short Bs_l[128][72];
  const int tid = threadIdx.x;
  const int lane = tid & 63, w = tid >> 6;
  const int wm = w >> 1, wn = w & 1;
  const int m0 = (blockIdx.x / NT) * 128, n0 = (blockIdx.x % NT) * 128;

  f4v acc[4][4];
#pragma unroll
  for (int i = 0; i < 4; ++i)
#pragma unroll
    for (int j = 0; j < 4; ++j) acc[i][j] = (f4v){0.f, 0.f, 0.f, 0.f};

  for (int kt = 0; kt < KD; kt += 64) {
    __syncthreads();
#pragma unroll
    for (int p = 0; p < 4; ++p) {
      int li = tid + p * 256;
      int row = li >> 3, kc = (li & 7) << 3;
      int m = m0 + row;
      int arow = REMAP ? ((m & 511) * 128 + c0 + (m >> 9)) : m;
      *(s8v*)&As_h[row][kc] = *(const s8v*)&Ah[(size_t)arow * KD + kt + kc];
      *(s8v*)&As_l[row][kc] = *(const s8v*)&Al[(size_t)arow * KD + kt + kc];
      *(s8v*)&Bs_h[row][kc] = *(const s8v*)&BTh[(size_t)(n0 + row) * KD + kt + kc];
      *(s8v*)&Bs_l[row][kc] = *(const s8v*)&BTl[(size_t)(n0 + row) * KD + kt + kc];
    }
    __syncthreads();
#pragma unroll
    for (int kk = 0; kk < 2; ++kk) {
      const int kb = kk * 32 + (lane >> 4) * 8;
      s8v ah[4], alo[4], bh[4], blo[4];
#pragma unroll
      for (int i = 0; i < 4; ++i) {
        int ra = wm * 64 + i * 16 + (lane & 15);
        int rb = wn * 64 + i * 16 + (lane & 15);
        ah[i]  = *(const s8v*)&As_h[ra][kb];
        alo[i] = *(const s8v*)&As_l[ra][kb];
        bh[i]  = *(const s8v*)&Bs_h[rb][kb];
        blo[i] = *(const s8v*)&Bs_l[rb][kb];
      }
#pragma unroll
      for (int mi = 0; mi < 4; ++mi)
#pragma unroll
        for (int ni = 0; ni < 4; ++ni) {
          acc[mi][ni] = __builtin_amdgcn_mfma_f32_16x16x32_bf16(alo[mi], bh[ni], acc[mi][ni], 0, 0, 0);
          acc[mi][ni] = __builtin_amdgcn_mfma_f32_16x16x32_bf16(ah[mi], blo[ni], acc[mi][ni], 0, 0, 0);
          acc[mi][ni] = __builtin_amdgcn_mfma_f32_16x16x32_bf16(ah[mi], bh[ni], acc[mi][ni], 0, 0, 0);
        }
    }
  }
#pragma unroll
  for (int mi = 0; mi < 4; ++mi) {
#pragma unroll
    for (int ni = 0; ni < 4; ++ni) {
      int n = n0 + wn * 64 + ni * 16 + (lane & 15);
      float bv = bias[n];
#pragma unroll
      for (int r = 0; r < 4; ++r) {
        int m = m0 + wm * 64 + mi * 16 + (lane >> 4) * 4 + r;
        float val = acc[mi][ni][r] + bv;
        if (OMODE == 1) {
          if (n < HH) {
            unsigned short hb = bf16_rne(val);
            unsigned short lb = bf16_rne(val - bf16_tof(hb));
            o_xeh[(size_t)m * KD + n] = hb;
            o_xel[(size_t)m * KD + n] = lb;
          } else {
            o_xp[(size_t)m * NC + (n - HH)] = val;
          }
        } else {
          o_xp[(size_t)m * NC + n] = val;
        }
      }
    }
  }
}

// ---------------- fused 3-layer MFMA scan ----------------
struct LayerArgs {
  const unsigned short* xin_h; const unsigned short* xin_l;
  const float* xp;
  const int* ain; const int* nin;
  int* aout; int* nout;
  unsigned short* hout_h; unsigned short* hout_l;
  unsigned int* hst;
  int* aT; int* dT;
  float* dd;
  int LL, c0, FIRST, active;
};
struct Args3 { LayerArgs l[3]; };

// 96 blocks x 512 threads; block b: layer = b>>5, rowblock = b&31 (16 rows).
// Phase A: B staged from PACKED weights (contiguous 1KB/wave per tile) via
// global_load_lds into wave-private 4-deep LDS ring, counted vmcnt(6),
// carry-over staging across steps (no per-step drain). LDS read at lane*16B
// is linear/conflict-free; global read is contiguous -> both sides optimal.
__global__ __launch_bounds__(512) void scan3_k(
    Args3 A3,
    const unsigned short* __restrict__ Upk,
    const float* __restrict__ Wa2, const float* __restrict__ ba2,
    const int* __restrict__ mask, int CH)
{
  const int lay = blockIdx.x >> 5;
  const LayerArgs La = A3.l[lay];
  if (!La.active) return;

  __shared__ __align__(16) unsigned short hh[SBR][520];
  __shared__ __align__(16) unsigned short hl[SBR][520];
  __shared__ __align__(16) unsigned short ring[8][4][2][512]; // wave x slot x plane x 1KB
  __shared__ float ya[SBR][644];
  __shared__ float pol[SBR][AA];
  __shared__ float sWa2[AA * 2];
  __shared__ float sba2[2];
  __shared__ int gB[SBR], gH[SBR], gX[SBR], gDP[SBR], sAT[SBR], sDT[SBR];

  const int tid = threadIdx.x;
  const int lane = tid & 63, w = tid >> 6;
  const int b0 = (blockIdx.x & 31) * SBR;
  const int ar = lane & 15, g = lane >> 4;
  const int cola = tid & 127, rb = tid >> 7;

  if (tid < AA * 2) sWa2[tid] = Wa2[tid];
  if (tid < 2) sba2[tid] = ba2[tid];
  if (tid < SBR) {
    sAT[tid] = La.FIRST ? 0 : La.aT[b0 + tid];
    sDT[tid] = La.FIRST ? 0 : La.dT[b0 + tid];
  }
#pragma unroll
  for (int r = 0; r < SBR; ++r) {
    unsigned int u = La.FIRST ? 0u : La.hst[(size_t)(b0 + r) * KD + tid];
    hh[r][tid] = (unsigned short)(u >> 16);
    hl[r][tid] = (unsigned short)(u & 0xffff);
  }
  __syncthreads();

  // packed weight base for this wave: 80 tiles x 2KB, consumption order
  const unsigned short* __restrict__ wbase = Upk + (size_t)w * 80 * 1024 + (size_t)lane * 8;

  const int br0 = b0 + 2 * w;
  const int br1 = br0 + 1;

  auto stage = [&](int j) {   // tile j -> slot j&3; contiguous 1KB per plane
    const int s = j & 3;
    const unsigned short* gh = wbase + (size_t)j * 1024;
    const unsigned short* gl = gh + 512;
    __builtin_amdgcn_global_load_lds(
        (const __attribute__((address_space(1))) void*)gh,
        (__attribute__((address_space(3))) void*)&ring[w][s][0][0], 16, 0, 0);
    __builtin_amdgcn_global_load_lds(
        (const __attribute__((address_space(1))) void*)gl,
        (__attribute__((address_space(3))) void*)&ring[w][s][1][0], 16, 0, 0);
  };

  for (int tl = 0; tl < CH; ++tl) {
    const int t = La.c0 + tl;
    const size_t xrow = (size_t)tl * BSZ + b0;

    // ---- phase A: Y = h @ Ucat; ring-staged B, counted vmcnt, carry-over ----
    f4v acc[5];
#pragma unroll
    for (int nt = 0; nt < 5; ++nt) acc[nt] = (f4v){0.f, 0.f, 0.f, 0.f};

    if (tl == 0) { stage(0); stage(1); stage(2); }

#pragma unroll
    for (int ks = 0; ks < 16; ++ks) {
      const int ko = ks * 32 + g * 8;
      s8v ah = *(const s8v*)&hh[ar][ko];
      s8v al = *(const s8v*)&hl[ar][ko];
#pragma unroll
      for (int nt = 0; nt < 5; ++nt) {
        const int j = ks * 5 + nt;
        int j3 = j + 3; if (j3 >= 80) j3 -= 80;   // wrap stages next step's 0..2
        stage(j3);
        asm volatile("s_waitcnt vmcnt(6)" ::: "memory");
        const int s = j & 3;
        s8v bh = *(const s8v*)&ring[w][s][0][lane * 8];   // own 16B: linear, conflict-free
        s8v bl = *(const s8v*)&ring[w][s][1][lane * 8];
        acc[nt] = __builtin_amdgcn_mfma_f32_16x16x32_bf16(al, bh, acc[nt], 0, 0, 0);
        acc[nt] = __builtin_amdgcn_mfma_f32_16x16x32_bf16(ah, bl, acc[nt], 0, 0, 0);
        acc[nt] = __builtin_amdgcn_mfma_f32_16x16x32_bf16(ah, bh, acc[nt], 0, 0, 0);
      }
    }
#pragma unroll
    for (int nt = 0; nt < 5; ++nt)
#pragma unroll
      for (int r = 0; r < 4; ++r)
        ya[g * 4 + r][w * 80 + nt * 16 + ar] = acc[nt][r];
    __syncthreads();

    // ---- phase B: hnew (regs) + pol (LDS) ----
    const float* __restrict__ xpb = La.xp + xrow * NC;
    float hnew_r[16];
#pragma unroll
    for (int r = 0; r < 16; ++r) hnew_r[r] = fast_tanh(xpb[(size_t)r * NC + tid] + ya[r][tid]);
#pragma unroll
    for (int q = 0; q < 4; ++q) {
      int r = q * 4 + rb;
      pol[r][cola] = fmaxf(xpb[(size_t)r * NC + HH + cola] + ya[r][HH + cola], 0.f);
    }
    __syncthreads();

    // ---- phase C+D: logits + gating (wave-local) ----
    {
      int A0 = (La.ain && t < LSEQ - 1) ? La.ain[(t + 1) * BSZ + br0] : 0;
      int A1 = (La.ain && t < LSEQ - 1) ? La.ain[(t + 1) * BSZ + br1] : 0;
      int DP0 = La.nin ? La.nin[t * BSZ + br0] : mask[br0 * LSEQ + t];
      int DP1 = La.nin ? La.nin[t * BSZ + br1] : mask[br1 * LSEQ + t];
      int mt0 = mask[br0 * LSEQ + t];
      int mt1 = mask[br1 * LSEQ + t];
      int mn0 = (t < LSEQ - 1) ? mask[br0 * LSEQ + t + 1] : 0;
      int mn1 = (t < LSEQ - 1) ? mask[br1 * LSEQ + t + 1] : 0;

      const int g16 = lane >> 4, li = lane & 15;
      const int rr = 2 * w + (g16 >> 1), j = g16 & 1;
      float p = 0.f;
#pragma unroll
      for (int i = 0; i < 8; ++i)
        p = fmaf(pol[rr][li + 16 * i], sWa2[(li + 16 * i) * 2 + j], p);
      p += __shfl_xor(p, 1); p += __shfl_xor(p, 2);
      p += __shfl_xor(p, 4); p += __shfl_xor(p, 8);
      float l00 = __shfl(p, 0)  + sba2[0];
      float l01 = __shfl(p, 16) + sba2[1];
      float l10 = __shfl(p, 32) + sba2[0];
      float l11 = __shfl(p, 48) + sba2[1];
      int E0 = mt0 * (1 - mn0), E1 = mt1 * (1 - mn1);
      int act0 = (l00 >= l01) ? 1 : 0;
      if (A0 > 0) act0 = 1;
      if (La.LL) act0 = 1;
      if (E0 > 0) act0 = 0;
      int act1 = (l10 >= l11) ? 1 : 0;
      if (A1 > 0) act1 = 1;
      if (La.LL) act1 = 1;
      if (E1 > 0) act1 = 0;
      int DT0 = sDT[2 * w], DT1 = sDT[2 * w + 1];
      int both0  = (1 - A0) * DP0 * act0 * DT0;
      int honly0 = DT0 * act0 * (A0 + (1 - A0) * (1 - DP0));
      int xonly0 = DP0 * (1 - A0) * (1 - act0 + act0 * (1 - DT0));
      int ndm0 = DP0 * (both0 + xonly0 + honly0);
      int aout0 = DP0 ? act0 : sAT[2 * w];
      int both1  = (1 - A1) * DP1 * act1 * DT1;
      int honly1 = DT1 * act1 * (A1 + (1 - A1) * (1 - DP1));
      int xonly1 = DP1 * (1 - A1) * (1 - act1 + act1 * (1 - DT1));
      int ndm1 = DP1 * (both1 + xonly1 + honly1);
      int aout1 = DP1 ? act1 : sAT[2 * w + 1];
      if (lane == 0) {
        gB[2 * w] = both0; gH[2 * w] = honly0; gX[2 * w] = xonly0; gDP[2 * w] = DP0;
        sAT[2 * w] = aout0; sDT[2 * w] = ndm0;
        gB[2 * w + 1] = both1; gH[2 * w + 1] = honly1; gX[2 * w + 1] = xonly1; gDP[2 * w + 1] = DP1;
        sAT[2 * w + 1] = aout1; sDT[2 * w + 1] = ndm1;
        if (La.aout) { La.aout[t * BSZ + br0] = aout0; La.aout[t * BSZ + br1] = aout1; }
        if (La.nout) { La.nout[t * BSZ + br0] = ndm0; La.nout[t * BSZ + br1] = ndm1; }
      }
    }
    __syncthreads();

    // ---- phase E: h update + outputs ----
#pragma unroll
    for (int r = 0; r < 16; ++r) {
      float vold = bf16_tof(hh[r][tid]) + bf16_tof(hl[r][tid]);
      float v;
      if (gB[r]) v = hnew_r[r];
      else if (gH[r]) v = vold;
      else if (gX[r]) {
        v = bf16_tof(La.xin_h[(xrow + r) * KD + tid]) + bf16_tof(La.xin_l[(xrow + r) * KD + tid]);
      } else v = 0.f;
      if (!gDP[r]) v = vold;
      unsigned short hi = bf16_rne(v);
      unsigned short lo = bf16_rne(v - bf16_tof(hi));
      hh[r][tid] = hi; hl[r][tid] = lo;
      if (La.hout_h) {
        La.hout_h[(xrow + r) * KD + tid] = hi;
        La.hout_l[(xrow + r) * KD + tid] = lo;
      }
      if (La.dd && t == LSEQ - 1) La.dd[(size_t)(b0 + r) * KD + tid] = v;
    }
    __syncthreads();
  }

#pragma unroll
  for (int r = 0; r < SBR; ++r)
    La.hst[(size_t)(b0 + r) * KD + tid] = ((unsigned int)hh[r][tid] << 16) | hl[r][tid];
  if (tid < SBR) { La.aT[b0 + tid] = sAT[tid]; La.dT[b0 + tid] = sDT[tid]; }
}

// ---------------- host ----------------
extern "C" void kernel_launch(void* const* d_in, const int* in_sizes, int n_in,
                              void* d_out, int out_size, void* d_ws, size_t ws_size,
                              hipStream_t stream)
{
  (void)in_sizes; (void)n_in; (void)out_size;
  const float* x    = (const float*)d_in[0];
  const int*   mask = (const int*)d_in[2];
  const float* Wemb = (const float*)d_in[3];
  const float* bemb = (const float*)d_in[4];
  const float* Wm   = (const float*)d_in[5];
  const float* Um   = (const float*)d_in[6];
  const float* bm   = (const float*)d_in[7];
  const float* Wa1  = (const float*)d_in[8];
  const float* Ua1  = (const float*)d_in[9];
  const float* ba1  = (const float*)d_in[10];
  const float* Wa2  = (const float*)d_in[11];
  const float* ba2  = (const float*)d_in[12];
  float* out = (float*)d_out;

  const size_t FIXED = (size_t)162 << 20;
  const size_t PER_CH = (size_t)12 << 20;
  int CH = 4;
  {
    const int cands[3] = {16, 8, 4};
    for (int i = 0; i < 3; ++i)
      if (FIXED + (size_t)cands[i] * PER_CH <= ws_size) { CH = cands[i]; break; }
  }
  const int NCH = LSEQ / CH;

  char* p = (char*)d_ws;
  auto alloc = [&](size_t bytes) { char* r = p; p += (bytes + 255) & ~(size_t)255; return r; };

  float* Ucat  = (float*)alloc((size_t)KD * NC * 4);
  float* Wcat  = (float*)alloc((size_t)KD * NC * 4);
  float* Wcomb = (float*)alloc((size_t)KD * NC * 4);
  float* bias1 = (float*)alloc(N1 * 4);
  float* bias2 = (float*)alloc(NC * 4);
  unsigned short* BT1h = (unsigned short*)alloc((size_t)N1 * KD * 2);
  unsigned short* BT1l = (unsigned short*)alloc((size_t)N1 * KD * 2);
  unsigned short* BT2h = (unsigned short*)alloc((size_t)NC * KD * 2);
  unsigned short* BT2l = (unsigned short*)alloc((size_t)NC * KD * 2);
  unsigned short* UTh  = (unsigned short*)alloc((size_t)NC * KD * 2);
  unsigned short* UTl  = (unsigned short*)alloc((size_t)NC * KD * 2);
  unsigned short* Upk  = (unsigned short*)alloc((size_t)8 * 80 * 1024 * 2);
  int* acts0 = (int*)alloc((size_t)LSEQ * BSZ * 4);
  int* ndms0 = (int*)alloc((size_t)LSEQ * BSZ * 4);
  int* acts1 = (int*)alloc((size_t)LSEQ * BSZ * 4);
  int* ndms1 = (int*)alloc((size_t)LSEQ * BSZ * 4);
  unsigned int* hst0 = (unsigned int*)alloc((size_t)BSZ * KD * 4);
  unsigned int* hst1 = (unsigned int*)alloc((size_t)BSZ * KD * 4);
  unsigned int* hst2 = (unsigned int*)alloc((size_t)BSZ * KD * 4);
  int* aT0 = (int*)alloc(BSZ * 4); int* dT0 = (int*)alloc(BSZ * 4);
  int* aT1 = (int*)alloc(BSZ * 4); int* dT1 = (int*)alloc(BSZ * 4);
  int* aT2 = (int*)alloc(BSZ * 4); int* dT2 = (int*)alloc(BSZ * 4);
  const size_t XEL = (size_t)BSZ * LSEQ * KD;
  unsigned short* xph = (unsigned short*)alloc(XEL * 2);
  unsigned short* xpl = (unsigned short*)alloc(XEL * 2);
  const size_t CE = (size_t)CH * BSZ * KD;
  unsigned short* xeh = (unsigned short*)alloc(CE * 2);
  unsigned short* xel = (unsigned short*)alloc(CE * 2);
  unsigned short* h0h[3], *h0l[3], *h1h[3], *h1l[3];
  for (int i = 0; i < 3; ++i) {
    h0h[i] = (unsigned short*)alloc(CE * 2); h0l[i] = (unsigned short*)alloc(CE * 2);
    h1h[i] = (unsigned short*)alloc(CE * 2); h1l[i] = (unsigned short*)alloc(CE * 2);
  }
  float* XP0 = (float*)alloc((size_t)CH * BSZ * NC * 4);
  float* XP1 = (float*)alloc((size_t)CH * BSZ * NC * 4);
  float* XP2 = (float*)alloc((size_t)CH * BSZ * NC * 4);

  concat_k<<<(KD * NC + 255) / 256, 256, 0, stream>>>(Um, Ua1, Wm, Wa1, bm, ba1, Ucat, Wcat, bias2);
  comb_k<<<KD, NC, 0, stream>>>(Wemb, Wcat, Wcomb);
  bcomb_k<<<1, NC, 0, stream>>>(bemb, Wcat, bias2, bias1);
  tsplit_k<<<dim3(16, 16), 256, 0, stream>>>(Wemb, HH, BT1h, BT1l, 0);
  tsplit_k<<<dim3(16, 20), 256, 0, stream>>>(Wcomb, NC, BT1h, BT1l, HH);
  tsplit_k<<<dim3(16, 20), 256, 0, stream>>>(Wcat, NC, BT2h, BT2l, 0);
  tsplit_k<<<dim3(16, 20), 256, 0, stream>>>(Ucat, NC, UTh, UTl, 0);
  upack_k<<<(8 * 80 * 2 * 64 + 255) / 256, 256, 0, stream>>>(UTh, UTl, Upk);
  splitx_k<<<(int)((XEL / 4 + 255) / 256), 256, 0, stream>>>(x, xph, xpl, (int)(XEL / 4));

  for (int s = 0; s < NCH + 4; ++s) {
    const int c0i = s, c1i = s - 2, c2i = s - 4;
    const bool a0 = (c0i >= 0 && c0i < NCH);
    const bool a1 = (c1i >= 0 && c1i < NCH);
    const bool a2 = (c2i >= 0 && c2i < NCH);
    const int s0 = a0 ? (c0i % 3) : 0, s1 = a1 ? (c1i % 3) : 0, s2 = a2 ? (c2i % 3) : 0;

    if (a0) gemm_k<1, 1><<<CH * 36, 256, 0, stream>>>(xph, xpl, BT1h, BT1l, bias1, 9, c0i * CH,
                                                      xeh, xel, XP0);
    if (a1) gemm_k<0, 2><<<CH * 20, 256, 0, stream>>>(h0h[s1], h0l[s1], BT2h, BT2l, bias2, 5, 0,
                                                      nullptr, nullptr, XP1);
    if (a2) gemm_k<0, 2><<<CH * 20, 256, 0, stream>>>(h1h[s2], h1l[s2], BT2h, BT2l, bias2, 5, 0,
                                                      nullptr, nullptr, XP2);

    Args3 A3{};
    A3.l[0] = LayerArgs{ xeh, xel, XP0, nullptr, nullptr, acts0, ndms0,
                         h0h[s0], h0l[s0], hst0, aT0, dT0, nullptr,
                         0, c0i * CH, c0i == 0, a0 ? 1 : 0 };
    A3.l[1] = LayerArgs{ h0h[s1], h0l[s1], XP1, acts0, ndms0, acts1, ndms1,
                         h1h[s1], h1l[s1], hst1, aT1, dT1, nullptr,
                         0, c1i * CH, c1i == 0, a1 ? 1 : 0 };
    A3.l[2] = LayerArgs{ h1h[s2], h1l[s2], XP2, acts1, ndms1, nullptr, nullptr,
                         nullptr, nullptr, hst2, aT2, dT2, out,
                         1, c2i * CH, c2i == 0, a2 ? 1 : 0 };
    scan3_k<<<96, 512, 0, stream>>>(A3, Upk, Wa2, ba2, mask, CH);
  }
}